// Round 1
// baseline (960.308 us; speedup 1.0000x reference)
//
#include <hip/hip_runtime.h>
#include <math.h>

typedef unsigned short u16;
typedef unsigned int u32;
typedef __attribute__((ext_vector_type(8))) short bf16x8;
typedef __attribute__((ext_vector_type(4))) float f32x4;

#define IMG 128
#define HWN 16384
#define DIMC 384
#define CDIM 1152
#define NBATCH 4
#define NHEAD 8
#define CHD 48

__device__ __forceinline__ u16 f2bf(float f) {
  union { float f; u32 u; } x; x.f = f;
  u32 r = x.u + 0x7fffu + ((x.u >> 16) & 1u);
  return (u16)(r >> 16);
}
__device__ __forceinline__ float bf2f(u16 v) {
  union { u32 u; float f; } x; x.u = ((u32)v) << 16;
  return x.f;
}

// ---------------- tiny: convert w_qkv to bf16 ----------------
__global__ void convert_wq_kernel(const float* __restrict__ in, u16* __restrict__ out, int n) {
  int i = blockIdx.x * 256 + threadIdx.x;
  if (i < n) out[i] = f2bf(in[i]);
}

// ---------------- K0: x [b,c,n] f32 -> xT [b,n,c] bf16 ----------------
__global__ __launch_bounds__(256) void transpose_x_kernel(const float* __restrict__ x,
                                                          u16* __restrict__ xT) {
  __shared__ float tile[32][33];
  int n0 = blockIdx.x * 32, c0 = blockIdx.y * 32, b = blockIdx.z;
  const float* xb = x + (size_t)b * DIMC * HWN;
  u16* xTb = xT + (size_t)b * HWN * DIMC;
  int tx = threadIdx.x & 31, ty = threadIdx.x >> 5;
#pragma unroll
  for (int i = 0; i < 32; i += 8)
    tile[ty + i][tx] = xb[(size_t)(c0 + ty + i) * HWN + n0 + tx];
  __syncthreads();
#pragma unroll
  for (int i = 0; i < 32; i += 8)
    xTb[(size_t)(n0 + ty + i) * DIMC + c0 + tx] = f2bf(tile[tx][ty + i]);
}

// ---------------- GEMM: C[M,N] = A[M,K] * B[N,K]^T (both bf16 row-major along K) ----
// 128x128 tile, BK=64, 4 waves of 64x64, mfma_f32_16x16x32_bf16
template <int BF16OUT>
__global__ __launch_bounds__(256) void gemm_bt_kernel(
    const u16* __restrict__ A, const u16* __restrict__ B, void* __restrict__ Cout,
    int M, int N, int K, int ldc,
    unsigned long long aStride, unsigned long long bStride, unsigned long long cStride) {
  __shared__ u16 As[128 * 72];
  __shared__ u16 Bs[128 * 72];
  int bz = blockIdx.z;
  const u16* Ab = A + (size_t)bz * aStride;
  const u16* Bb = B + (size_t)bz * bStride;
  int m0 = blockIdx.x * 128, n0 = blockIdx.y * 128;
  int t = threadIdx.x;
  int wave = t >> 6, lane = t & 63;
  int wm = (wave >> 1) * 64, wn = (wave & 1) * 64;
  int lr = lane & 15, lk = (lane >> 4) * 8;

  f32x4 acc[4][4];
#pragma unroll
  for (int mi = 0; mi < 4; mi++)
#pragma unroll
    for (int ni = 0; ni < 4; ni++) acc[mi][ni] = (f32x4){0.f, 0.f, 0.f, 0.f};

  for (int k0 = 0; k0 < K; k0 += 64) {
#pragma unroll
    for (int i = 0; i < 4; i++) {
      int chunk = t + i * 256;          // 0..1023
      int row = chunk >> 3;             // 0..127
      int c8 = (chunk & 7) * 8;         // 0..56
      *(bf16x8*)&As[row * 72 + c8] =
          *(const bf16x8*)&Ab[(size_t)(m0 + row) * K + k0 + c8];
      *(bf16x8*)&Bs[row * 72 + c8] =
          *(const bf16x8*)&Bb[(size_t)(n0 + row) * K + k0 + c8];
    }
    __syncthreads();
#pragma unroll
    for (int kk = 0; kk < 2; kk++) {
      bf16x8 af[4], bfr[4];
#pragma unroll
      for (int mi = 0; mi < 4; mi++)
        af[mi] = *(const bf16x8*)&As[(wm + mi * 16 + lr) * 72 + kk * 32 + lk];
#pragma unroll
      for (int ni = 0; ni < 4; ni++)
        bfr[ni] = *(const bf16x8*)&Bs[(wn + ni * 16 + lr) * 72 + kk * 32 + lk];
#pragma unroll
      for (int mi = 0; mi < 4; mi++)
#pragma unroll
        for (int ni = 0; ni < 4; ni++)
          acc[mi][ni] = __builtin_amdgcn_mfma_f32_16x16x32_bf16(af[mi], bfr[ni],
                                                                acc[mi][ni], 0, 0, 0);
    }
    __syncthreads();
  }
  int r0 = (lane >> 4) * 4;
#pragma unroll
  for (int mi = 0; mi < 4; mi++)
#pragma unroll
    for (int ni = 0; ni < 4; ni++)
#pragma unroll
      for (int r = 0; r < 4; r++) {
        int row = m0 + wm + mi * 16 + r0 + r;
        int col = n0 + wn + ni * 16 + (lane & 15);
        size_t idx = (size_t)bz * cStride + (size_t)row * ldc + col;
        if (BF16OUT)
          ((u16*)Cout)[idx] = f2bf(acc[mi][ni][r]);
        else
          ((float*)Cout)[idx] = acc[mi][ni][r];
      }
}

// ---------------- K2a: depthwise 3x3 for v channels -> vT [n, c] bf16 ----------------
__global__ __launch_bounds__(256) void dwconv_v_kernel(const u16* __restrict__ qkvT,
                                                       const float* __restrict__ w_dw,
                                                       u16* __restrict__ vT) {
  __shared__ float wl[DIMC * 9];
  int y = blockIdx.x, b = blockIdx.y;
  const u16* src = qkvT + (size_t)b * HWN * CDIM;
  u16* dst = vT + (size_t)b * HWN * DIMC;
  for (int i = threadIdx.x; i < DIMC * 9; i += 256) wl[i] = w_dw[768 * 9 + i];
  __syncthreads();
  int c = threadIdx.x & 63;
  int xo = threadIdx.x >> 6;  // 0..3
#pragma unroll
  for (int cc = 0; cc < 6; cc++) {
    int ch = cc * 64 + c;       // 0..383
    int gch = 768 + ch;
    float w[9];
#pragma unroll
    for (int i = 0; i < 9; i++) w[i] = wl[ch * 9 + i];
    for (int xx = 0; xx < 32; xx++) {
      int x = xo + xx * 4;
      float a = 0.f;
#pragma unroll
      for (int dy = -1; dy <= 1; dy++) {
        int yn = y + dy;
        if (yn < 0 || yn > 127) continue;
#pragma unroll
        for (int dx = -1; dx <= 1; dx++) {
          int xn = x + dx;
          if (xn < 0 || xn > 127) continue;
          a += bf2f(src[(size_t)(yn * IMG + xn) * CDIM + gch]) * w[(dy + 1) * 3 + dx + 1];
        }
      }
      dst[(size_t)(y * IMG + x) * DIMC + ch] = f2bf(a);
    }
  }
}

// ---------------- K2b: dwconv for q,k of one head + Gram-matrix partials ----------------
// grid (16 ytiles, 8 heads, 4 b), 256 threads. Per block: 8 image rows.
// partials layout per slot: [2304 S entries][48 q-norm^2][48 k-norm^2] (stride 2400)
__global__ __launch_bounds__(256) void dwconv_qk_s_kernel(const u16* __restrict__ qkvT,
                                                          const float* __restrict__ w_dw,
                                                          float* __restrict__ partials) {
  __shared__ u16 qk[96 * 136];       // [c96][x+pad]
  __shared__ float wl[96 * 9];
  __shared__ float Sred[4 * 2304];
  __shared__ float nred[3 * 256];
  int yt = blockIdx.x, h = blockIdx.y, b = blockIdx.z;
  const u16* src = qkvT + (size_t)b * HWN * CDIM;
  int lane31 = threadIdx.x & 31;
  int xg = threadIdx.x >> 5;  // 0..7
  int wave = threadIdx.x >> 6, lane = threadIdx.x & 63;
  int lr = lane & 15, lk = (lane >> 4) * 8;

  for (int i = threadIdx.x; i < 96 * 9; i += 256) {
    int c96 = i / 9, r = i % 9;
    int gch = (c96 < CHD) ? h * CHD + c96 : DIMC + h * CHD + (c96 - CHD);
    wl[i] = w_dw[gch * 9 + r];
  }
  f32x4 acc[3][3];
#pragma unroll
  for (int mi = 0; mi < 3; mi++)
#pragma unroll
    for (int ni = 0; ni < 3; ni++) acc[mi][ni] = (f32x4){0.f, 0.f, 0.f, 0.f};
  float nrm[3] = {0.f, 0.f, 0.f};
  __syncthreads();

  for (int yy = 0; yy < 8; yy++) {
    int y = yt * 8 + yy;
    // phase A: dwconv -> LDS (bf16)
#pragma unroll
    for (int cc = 0; cc < 3; cc++) {
      int c96 = cc * 32 + lane31;
      int gch = (c96 < CHD) ? h * CHD + c96 : DIMC + h * CHD + (c96 - CHD);
      float w[9];
#pragma unroll
      for (int i = 0; i < 9; i++) w[i] = wl[c96 * 9 + i];
      for (int xx = 0; xx < 16; xx++) {
        int x = xg + xx * 8;
        float a = 0.f;
#pragma unroll
        for (int dy = -1; dy <= 1; dy++) {
          int yn = y + dy;
          if (yn < 0 || yn > 127) continue;
#pragma unroll
          for (int dx = -1; dx <= 1; dx++) {
            int xn = x + dx;
            if (xn < 0 || xn > 127) continue;
            a += bf2f(src[(size_t)(yn * IMG + xn) * CDIM + gch]) * w[(dy + 1) * 3 + dx + 1];
          }
        }
        u16 hv = f2bf(a);
        qk[c96 * 136 + x] = hv;
        float ar = bf2f(hv);
        nrm[cc] += ar * ar;
      }
    }
    __syncthreads();
    // phase B: S += q_tile * k_tile^T over this row; wave w owns x-chunk w*32
    {
      int kofs = wave * 32 + lk;
      bf16x8 af[3], bfr[3];
#pragma unroll
      for (int mi = 0; mi < 3; mi++)
        af[mi] = *(const bf16x8*)&qk[(mi * 16 + lr) * 136 + kofs];
#pragma unroll
      for (int ni = 0; ni < 3; ni++)
        bfr[ni] = *(const bf16x8*)&qk[(48 + ni * 16 + lr) * 136 + kofs];
#pragma unroll
      for (int mi = 0; mi < 3; mi++)
#pragma unroll
        for (int ni = 0; ni < 3; ni++)
          acc[mi][ni] = __builtin_amdgcn_mfma_f32_16x16x32_bf16(af[mi], bfr[ni],
                                                                acc[mi][ni], 0, 0, 0);
    }
    __syncthreads();
  }

  // write per-wave S to LDS, reduce across waves
#pragma unroll
  for (int mi = 0; mi < 3; mi++)
#pragma unroll
    for (int ni = 0; ni < 3; ni++)
#pragma unroll
      for (int r = 0; r < 4; r++) {
        int crow = mi * 16 + (lane >> 4) * 4 + r;
        int dcol = ni * 16 + (lane & 15);
        Sred[wave * 2304 + crow * 48 + dcol] = acc[mi][ni][r];
      }
#pragma unroll
  for (int cc = 0; cc < 3; cc++) nred[cc * 256 + threadIdx.x] = nrm[cc];
  __syncthreads();

  float* pout = partials + ((size_t)((b * NHEAD + h) * 16 + yt)) * 2400;
  for (int idx = threadIdx.x; idx < 2304; idx += 256) {
    float s = 0.f;
#pragma unroll
    for (int w = 0; w < 4; w++) s += Sred[w * 2304 + idx];
    pout[idx] = s;
  }
  if (threadIdx.x < 96) {
    int cc = threadIdx.x >> 5, l = threadIdx.x & 31;
    float s = 0.f;
#pragma unroll
    for (int g = 0; g < 8; g++) s += nred[cc * 256 + g * 32 + l];
    pout[2304 + threadIdx.x] = s;
  }
}

// ---------------- K3a: reduce partials, normalize, softmax -> attn [b,h,48,48] f32 ----
__global__ __launch_bounds__(256) void softmax_kernel(const float* __restrict__ partials,
                                                      const float* __restrict__ temp,
                                                      float* __restrict__ attn) {
  __shared__ float S[2400];
  int h = blockIdx.x, b = blockIdx.y;
  const float* p = partials + ((size_t)(b * NHEAD + h) * 16) * 2400;
  for (int idx = threadIdx.x; idx < 2400; idx += 256) {
    float s = 0.f;
#pragma unroll
    for (int yt = 0; yt < 16; yt++) s += p[yt * 2400 + idx];
    S[idx] = s;
  }
  __syncthreads();
  float tf = temp[h];
  float* A = attn + (size_t)(b * NHEAD + h) * 2304;
  if (threadIdx.x < CHD) {
    int c = threadIdx.x;
    float nq = fmaxf(sqrtf(S[2304 + c]), 1e-12f);
    float mx = -1e30f;
    for (int d = 0; d < CHD; d++) {
      float nk = fmaxf(sqrtf(S[2304 + 48 + d]), 1e-12f);
      float v = S[c * 48 + d] * tf / (nq * nk);
      S[c * 48 + d] = v;
      mx = fmaxf(mx, v);
    }
    float sum = 0.f;
    for (int d = 0; d < CHD; d++) {
      float e = expf(S[c * 48 + d] - mx);
      S[c * 48 + d] = e;
      sum += e;
    }
    float inv = 1.f / sum;
    for (int d = 0; d < CHD; d++) A[c * 48 + d] = S[c * 48 + d] * inv;
  }
}

// ---------------- K3b: Mf[b,o,h*48+d] = sum_c w_proj[o,h*48+c]*attn[b,h,c,d] (bf16) ----
__global__ __launch_bounds__(256) void build_mf_kernel(const float* __restrict__ attn,
                                                       const float* __restrict__ w_proj,
                                                       u16* __restrict__ Mf) {
  __shared__ float al[NHEAD * 2304];
  int b = blockIdx.y, o0 = blockIdx.x * 32;
  for (int i = threadIdx.x; i < NHEAD * 2304; i += 256) al[i] = attn[(size_t)b * NHEAD * 2304 + i];
  __syncthreads();
  for (int idx = threadIdx.x; idx < 32 * DIMC; idx += 256) {
    int ol = idx / DIMC, cp = idx % DIMC;
    int o = o0 + ol, h = cp / CHD, d = cp % CHD;
    float s = 0.f;
#pragma unroll
    for (int c = 0; c < CHD; c++)
      s += w_proj[(size_t)o * DIMC + h * CHD + c] * al[h * 2304 + c * 48 + d];
    Mf[((size_t)b * DIMC + o) * DIMC + cp] = f2bf(s);
  }
}

// ---------------- launch ----------------
extern "C" void kernel_launch(void* const* d_in, const int* in_sizes, int n_in,
                              void* d_out, int out_size, void* d_ws, size_t ws_size,
                              hipStream_t stream) {
  const float* x      = (const float*)d_in[0];
  const float* w_qkv  = (const float*)d_in[1];
  const float* w_dw   = (const float*)d_in[2];
  const float* w_proj = (const float*)d_in[3];
  const float* temp   = (const float*)d_in[4];
  float* out = (float*)d_out;

  char* ws = (char*)d_ws;
  size_t off = 0;
  u16* qkvT = (u16*)(ws + off);            // [b][n][1152] bf16
  off += (size_t)NBATCH * HWN * CDIM * 2;  // 150,994,944
  size_t xT_off = off;
  u16* xT = (u16*)(ws + off);              // [b][n][384] bf16
  off += (size_t)NBATCH * HWN * DIMC * 2;  // 50,331,648
  float* partials = (float*)(ws + off);    // [b*8*16][2400]
  off += (size_t)NBATCH * NHEAD * 16 * 2400 * 4;
  float* attn = (float*)(ws + off);        // [b][h][48][48]
  off += (size_t)NBATCH * NHEAD * 2304 * 4;
  u16* Mf = (u16*)(ws + off);              // [b][384][384] bf16
  off += (size_t)NBATCH * DIMC * DIMC * 2;
  u16* wq16 = (u16*)(ws + off);            // [1152][384] bf16
  off += (size_t)CDIM * DIMC * 2;
  u16* vT = (u16*)(ws + xT_off);           // alias xT (dead after K1)

  if (ws_size < off) return;  // workspace too small: fail loudly (zero output)

  // w_qkv -> bf16
  convert_wq_kernel<<<dim3((CDIM * DIMC + 255) / 256), dim3(256), 0, stream>>>(
      w_qkv, wq16, CDIM * DIMC);
  // x -> xT bf16
  transpose_x_kernel<<<dim3(HWN / 32, DIMC / 32, NBATCH), dim3(256), 0, stream>>>(x, xT);
  // qkvT[n,o] = xT[n,:] . w_qkv[o,:]
  gemm_bt_kernel<1><<<dim3(HWN / 128, CDIM / 128, NBATCH), dim3(256), 0, stream>>>(
      xT, wq16, (void*)qkvT, HWN, CDIM, DIMC, CDIM,
      (unsigned long long)HWN * DIMC, 0ULL, (unsigned long long)HWN * CDIM);
  // v depthwise conv
  dwconv_v_kernel<<<dim3(IMG, NBATCH), dim3(256), 0, stream>>>(qkvT, w_dw, vT);
  // q,k depthwise conv + Gram partials
  dwconv_qk_s_kernel<<<dim3(16, NHEAD, NBATCH), dim3(256), 0, stream>>>(qkvT, w_dw, partials);
  // softmax
  softmax_kernel<<<dim3(NHEAD, NBATCH), dim3(256), 0, stream>>>(partials, temp, attn);
  // fold attn into projection
  build_mf_kernel<<<dim3(DIMC / 32, NBATCH), dim3(256), 0, stream>>>(attn, w_proj, Mf);
  // out[b,o,n] = Mf[b,o,:] . vT[b,n,:]
  gemm_bt_kernel<0><<<dim3(DIMC / 128, HWN / 128, NBATCH), dim3(256), 0, stream>>>(
      Mf, vT, (void*)out, DIMC, HWN, DIMC, HWN,
      (unsigned long long)DIMC * DIMC, (unsigned long long)HWN * DIMC,
      (unsigned long long)DIMC * HWN);
}

// Round 2
// 503.711 us; speedup vs baseline: 1.9065x; 1.9065x over previous
//
#include <hip/hip_runtime.h>
#include <math.h>

typedef unsigned short u16;
typedef unsigned int u32;
typedef __attribute__((ext_vector_type(8))) short bf16x8;
typedef __attribute__((ext_vector_type(4))) float f32x4;

#define IMG 128
#define HWN 16384
#define DIMC 384
#define CDIM 1152
#define NBATCH 4
#define NHEAD 8
#define CHD 48
#define KC 8

__device__ __forceinline__ u16 f2bf(float f) {
  union { float f; u32 u; } x; x.f = f;
  u32 r = x.u + 0x7fffu + ((x.u >> 16) & 1u);
  return (u16)(r >> 16);
}
__device__ __forceinline__ float bf2f(u16 v) {
  union { u32 u; float f; } x; x.u = ((u32)v) << 16;
  return x.f;
}

// ---------------- tiny: convert w_qkv to bf16 ----------------
__global__ void convert_wq_kernel(const float* __restrict__ in, u16* __restrict__ out, int n) {
  int i = blockIdx.x * 256 + threadIdx.x;
  if (i < n) out[i] = f2bf(in[i]);
}

// ---------------- K0: x [c,n] f32 -> xT [n,c] bf16 (one batch) ----------------
__global__ __launch_bounds__(256) void transpose_x_kernel(const float* __restrict__ xb,
                                                          u16* __restrict__ xTb) {
  __shared__ float tile[32][33];
  int n0 = blockIdx.x * 32, c0 = blockIdx.y * 32;
  int tx = threadIdx.x & 31, ty = threadIdx.x >> 5;
#pragma unroll
  for (int i = 0; i < 32; i += 8)
    tile[ty + i][tx] = xb[(size_t)(c0 + ty + i) * HWN + n0 + tx];
  __syncthreads();
#pragma unroll
  for (int i = 0; i < 32; i += 8)
    xTb[(size_t)(n0 + ty + i) * DIMC + c0 + tx] = f2bf(tile[tx][ty + i]);
}

// ---------------- GEMM: C[M,N] = A[M,:K] * B[N,:K]^T, strided leading dims ----
template <int BF16OUT>
__global__ __launch_bounds__(256) void gemm_bt_kernel(
    const u16* __restrict__ A, const u16* __restrict__ B, void* __restrict__ Cout,
    int K, int lda, int ldb, int ldc,
    unsigned long long aStride, unsigned long long bStride, unsigned long long cStride) {
  __shared__ u16 As[128 * 72];
  __shared__ u16 Bs[128 * 72];
  int bz = blockIdx.z;
  const u16* Ab = A + (size_t)bz * aStride;
  const u16* Bb = B + (size_t)bz * bStride;
  int m0 = blockIdx.x * 128, n0 = blockIdx.y * 128;
  int t = threadIdx.x;
  int wave = t >> 6, lane = t & 63;
  int wm = (wave >> 1) * 64, wn = (wave & 1) * 64;
  int lr = lane & 15, lk = (lane >> 4) * 8;

  f32x4 acc[4][4];
#pragma unroll
  for (int mi = 0; mi < 4; mi++)
#pragma unroll
    for (int ni = 0; ni < 4; ni++) acc[mi][ni] = (f32x4){0.f, 0.f, 0.f, 0.f};

  for (int k0 = 0; k0 < K; k0 += 64) {
#pragma unroll
    for (int i = 0; i < 4; i++) {
      int chunk = t + i * 256;          // 0..1023
      int row = chunk >> 3;             // 0..127
      int c8 = (chunk & 7) * 8;         // 0..56
      *(bf16x8*)&As[row * 72 + c8] =
          *(const bf16x8*)&Ab[(size_t)(m0 + row) * lda + k0 + c8];
      *(bf16x8*)&Bs[row * 72 + c8] =
          *(const bf16x8*)&Bb[(size_t)(n0 + row) * ldb + k0 + c8];
    }
    __syncthreads();
#pragma unroll
    for (int kk = 0; kk < 2; kk++) {
      bf16x8 af[4], bfr[4];
#pragma unroll
      for (int mi = 0; mi < 4; mi++)
        af[mi] = *(const bf16x8*)&As[(wm + mi * 16 + lr) * 72 + kk * 32 + lk];
#pragma unroll
      for (int ni = 0; ni < 4; ni++)
        bfr[ni] = *(const bf16x8*)&Bs[(wn + ni * 16 + lr) * 72 + kk * 32 + lk];
#pragma unroll
      for (int mi = 0; mi < 4; mi++)
#pragma unroll
        for (int ni = 0; ni < 4; ni++)
          acc[mi][ni] = __builtin_amdgcn_mfma_f32_16x16x32_bf16(af[mi], bfr[ni],
                                                                acc[mi][ni], 0, 0, 0);
    }
    __syncthreads();
  }
  int r0 = (lane >> 4) * 4;
#pragma unroll
  for (int mi = 0; mi < 4; mi++)
#pragma unroll
    for (int ni = 0; ni < 4; ni++)
#pragma unroll
      for (int r = 0; r < 4; r++) {
        int row = m0 + wm + mi * 16 + r0 + r;
        int col = n0 + wn + ni * 16 + (lane & 15);
        size_t idx = (size_t)bz * cStride + (size_t)row * ldc + col;
        if (BF16OUT)
          ((u16*)Cout)[idx] = f2bf(acc[mi][ni][r]);
        else
          ((float*)Cout)[idx] = acc[mi][ni][r];
      }
}

// ---------------- K2: depthwise 3x3 for ALL channels, 128-ch groups ----------------
// grid (128 y, 9 cg); writes conv output pixel-major + q/k norm^2 partials per y.
__global__ __launch_bounds__(256) void dwconv_all_kernel(const u16* __restrict__ src,
                                                         const float* __restrict__ w_dw,
                                                         u16* __restrict__ dst,
                                                         float* __restrict__ nrmp) {
  __shared__ float wl[1152];      // 128 ch * 9 taps
  __shared__ float nl[16][128];
  int y = blockIdx.x, cg = blockIdx.y;
  int t = threadIdx.x;
  int c8 = t & 15, xg = t >> 4;
  int ch0 = cg * 128 + c8 * 8;

  for (int i = t; i < 1152; i += 256) wl[i] = w_dw[cg * 1152 + i];
  __syncthreads();
  float w[8][9];
#pragma unroll
  for (int j = 0; j < 8; j++)
#pragma unroll
    for (int r = 0; r < 9; r++) w[j][r] = wl[(c8 * 8 + j) * 9 + r];

  float norm2[8] = {0.f, 0.f, 0.f, 0.f, 0.f, 0.f, 0.f, 0.f};
#pragma unroll
  for (int i = 0; i < 8; i++) {
    int x = xg + i * 16;
    float acc[8] = {0.f, 0.f, 0.f, 0.f, 0.f, 0.f, 0.f, 0.f};
#pragma unroll
    for (int dy = -1; dy <= 1; dy++) {
      int yn = y + dy;
      if ((unsigned)yn > 127u) continue;
#pragma unroll
      for (int dx = -1; dx <= 1; dx++) {
        int xn = x + dx;
        if ((unsigned)xn > 127u) continue;
        bf16x8 vv = *(const bf16x8*)&src[(size_t)(yn * IMG + xn) * CDIM + ch0];
#pragma unroll
        for (int j = 0; j < 8; j++)
          acc[j] += bf2f((u16)vv[j]) * w[j][(dy + 1) * 3 + dx + 1];
      }
    }
    bf16x8 o;
#pragma unroll
    for (int j = 0; j < 8; j++) {
      o[j] = (short)f2bf(acc[j]);
      norm2[j] += acc[j] * acc[j];
    }
    *(bf16x8*)&dst[(size_t)(y * IMG + x) * CDIM + ch0] = o;
  }

  if (cg < 6) {  // q,k channels: 0..768
#pragma unroll
    for (int j = 0; j < 8; j++) nl[xg][c8 * 8 + j] = norm2[j];
    __syncthreads();
    if (t < 128) {
      float s = 0.f;
#pragma unroll
      for (int g = 0; g < 16; g++) s += nl[g][t];
      nrmp[y * 768 + cg * 128 + t] = s;
    }
  }
}

// ---------------- K3: Gram S = q . k^T per (b,h), K split in 8 chunks ----------------
__global__ __launch_bounds__(256) void gram_kernel(const u16* __restrict__ qkvC,
                                                   float* __restrict__ partials) {
  __shared__ u16 qk[96 * 136];
  __shared__ float Sred[4 * 2304];
  int kc = blockIdx.x, h = blockIdx.y, b = blockIdx.z;
  const u16* src = qkvC + (size_t)b * HWN * CDIM;
  int t = threadIdx.x, wave = t >> 6, lane = t & 63;
  int lr = lane & 15, lk = (lane >> 4) * 8;

  f32x4 acc[3][3];
#pragma unroll
  for (int mi = 0; mi < 3; mi++)
#pragma unroll
    for (int ni = 0; ni < 3; ni++) acc[mi][ni] = (f32x4){0.f, 0.f, 0.f, 0.f};

  int n00 = kc * 2048;
  for (int tile = 0; tile < 16; tile++) {
    int n0 = n00 + tile * 128;
    __syncthreads();
#pragma unroll
    for (int u = 0; u < 6; u++) {
      int idx = t + u * 256;          // 0..1535
      int c8 = idx % 12, n = idx / 12;
      int gch = (c8 < 6) ? h * CHD + c8 * 8 : DIMC + h * CHD + (c8 - 6) * 8;
      bf16x8 vv = *(const bf16x8*)&src[(size_t)(n0 + n) * CDIM + gch];
      int row = c8 * 8;
#pragma unroll
      for (int j = 0; j < 8; j++) qk[(row + j) * 136 + n] = (u16)vv[j];
    }
    __syncthreads();
    int kofs = wave * 32 + lk;
    bf16x8 af[3], bfr[3];
#pragma unroll
    for (int mi = 0; mi < 3; mi++)
      af[mi] = *(const bf16x8*)&qk[(mi * 16 + lr) * 136 + kofs];
#pragma unroll
    for (int ni = 0; ni < 3; ni++)
      bfr[ni] = *(const bf16x8*)&qk[(48 + ni * 16 + lr) * 136 + kofs];
#pragma unroll
    for (int mi = 0; mi < 3; mi++)
#pragma unroll
      for (int ni = 0; ni < 3; ni++)
        acc[mi][ni] = __builtin_amdgcn_mfma_f32_16x16x32_bf16(af[mi], bfr[ni],
                                                              acc[mi][ni], 0, 0, 0);
  }

#pragma unroll
  for (int mi = 0; mi < 3; mi++)
#pragma unroll
    for (int ni = 0; ni < 3; ni++)
#pragma unroll
      for (int r = 0; r < 4; r++) {
        int crow = mi * 16 + (lane >> 4) * 4 + r;
        int dcol = ni * 16 + (lane & 15);
        Sred[wave * 2304 + crow * 48 + dcol] = acc[mi][ni][r];
      }
  __syncthreads();
  float* pout = partials + ((size_t)((b * NHEAD + h) * KC + kc)) * 2304;
  for (int idx = t; idx < 2304; idx += 256) {
    float s = 0.f;
#pragma unroll
    for (int w = 0; w < 4; w++) s += Sred[w * 2304 + idx];
    pout[idx] = s;
  }
}

// ---------------- K4: reduce partials+norms, normalize, softmax -> attn ----------------
__global__ __launch_bounds__(256) void softmax_kernel(const float* __restrict__ partials,
                                                      const float* __restrict__ nrmp,
                                                      const float* __restrict__ temp,
                                                      float* __restrict__ attn) {
  __shared__ float S[2304];
  __shared__ float nq[48], nk[48];
  int h = blockIdx.x, b = blockIdx.y;
  const float* p = partials + (size_t)(b * NHEAD + h) * KC * 2304;
  for (int idx = threadIdx.x; idx < 2304; idx += 256) {
    float s = 0.f;
#pragma unroll
    for (int kc = 0; kc < KC; kc++) s += p[kc * 2304 + idx];
    S[idx] = s;
  }
  if (threadIdx.x < 96) {
    int tq = threadIdx.x;
    int c = (tq < 48) ? tq : tq - 48;
    int ch = (tq < 48) ? h * CHD + c : DIMC + h * CHD + c;
    float s = 0.f;
    for (int y = 0; y < 128; y++) s += nrmp[(size_t)b * 128 * 768 + y * 768 + ch];
    float nv = fmaxf(sqrtf(s), 1e-12f);
    if (tq < 48) nq[c] = nv; else nk[c] = nv;
  }
  __syncthreads();
  float tf = temp[h];
  float* A = attn + (size_t)(b * NHEAD + h) * 2304;
  if (threadIdx.x < CHD) {
    int c = threadIdx.x;
    float inq = 1.f / nq[c];
    float mx = -1e30f;
    float row[48];
    for (int d = 0; d < CHD; d++) {
      float v = S[c * 48 + d] * tf * inq / nk[d];
      row[d] = v;
      mx = fmaxf(mx, v);
    }
    float sum = 0.f;
    for (int d = 0; d < CHD; d++) {
      float e = expf(row[d] - mx);
      row[d] = e;
      sum += e;
    }
    float inv = 1.f / sum;
    for (int d = 0; d < CHD; d++) A[c * 48 + d] = row[d] * inv;
  }
}

// ---------------- K5: Mf[b,o,h*48+d] = sum_c w_proj[o,h*48+c]*attn[b,h,c,d] ----------
__global__ __launch_bounds__(256) void build_mf_kernel(const float* __restrict__ attn,
                                                       const float* __restrict__ w_proj,
                                                       u16* __restrict__ Mf) {
  __shared__ float al[NHEAD * 2304];
  int b = blockIdx.y, o0 = blockIdx.x * 32;
  for (int i = threadIdx.x; i < NHEAD * 2304; i += 256)
    al[i] = attn[(size_t)b * NHEAD * 2304 + i];
  __syncthreads();
  for (int idx = threadIdx.x; idx < 32 * DIMC; idx += 256) {
    int ol = idx / DIMC, cp = idx % DIMC;
    int o = o0 + ol, h = cp / CHD, d = cp % CHD;
    float s = 0.f;
#pragma unroll
    for (int c = 0; c < CHD; c++)
      s += w_proj[(size_t)o * DIMC + h * CHD + c] * al[h * 2304 + c * 48 + d];
    Mf[((size_t)b * DIMC + o) * DIMC + cp] = f2bf(s);
  }
}

// ---------------- launch ----------------
extern "C" void kernel_launch(void* const* d_in, const int* in_sizes, int n_in,
                              void* d_out, int out_size, void* d_ws, size_t ws_size,
                              hipStream_t stream) {
  const float* x      = (const float*)d_in[0];
  const float* w_qkv  = (const float*)d_in[1];
  const float* w_dw   = (const float*)d_in[2];
  const float* w_proj = (const float*)d_in[3];
  const float* temp   = (const float*)d_in[4];
  float* out = (float*)d_out;

  char* ws = (char*)d_ws;
  size_t off = 0;
  u16* qkvC = (u16*)(ws + off);              // [b][n][1152] conv output, bf16
  off += (size_t)NBATCH * HWN * CDIM * 2;    // 150,994,944
  u16* qkvT_b = (u16*)(ws + off);            // [n][1152] single-batch gemm1 out
  off += (size_t)HWN * CDIM * 2;             // 37,748,736
  size_t xT_off = off;
  u16* xT_b = (u16*)(ws + off);              // [n][384] single-batch
  off += (size_t)HWN * DIMC * 2;             // 12,582,912
  u16* wq16 = (u16*)(ws + off);
  off += (size_t)CDIM * DIMC * 2;            // 884,736
  float* nrmp = (float*)(ws + off);          // [b][128][768]
  off += (size_t)NBATCH * 128 * 768 * 4;     // 1,572,864
  // aliases into dead xT_b region (used only after last gemm1):
  float* partials = (float*)(ws + xT_off);                       // 2,359,296
  float* attn = (float*)(ws + xT_off + 2359296);                 //   294,912
  u16* Mf = (u16*)(ws + xT_off + 2359296 + 294912);              // 1,179,648

  if (ws_size < off) return;  // fail loudly (zero output) if workspace too small

  convert_wq_kernel<<<dim3((CDIM * DIMC + 255) / 256), dim3(256), 0, stream>>>(
      w_qkv, wq16, CDIM * DIMC);

  for (int b = 0; b < NBATCH; b++) {
    transpose_x_kernel<<<dim3(HWN / 32, DIMC / 32), dim3(256), 0, stream>>>(
        x + (size_t)b * DIMC * HWN, xT_b);
    gemm_bt_kernel<1><<<dim3(HWN / 128, CDIM / 128, 1), dim3(256), 0, stream>>>(
        xT_b, wq16, (void*)qkvT_b, DIMC, DIMC, DIMC, CDIM, 0ULL, 0ULL, 0ULL);
    dwconv_all_kernel<<<dim3(IMG, 9), dim3(256), 0, stream>>>(
        qkvT_b, w_dw, qkvC + (size_t)b * HWN * CDIM, nrmp + (size_t)b * 128 * 768);
  }

  gram_kernel<<<dim3(KC, NHEAD, NBATCH), dim3(256), 0, stream>>>(qkvC, partials);
  softmax_kernel<<<dim3(NHEAD, NBATCH), dim3(256), 0, stream>>>(partials, nrmp, temp, attn);
  build_mf_kernel<<<dim3(DIMC / 32, NBATCH), dim3(256), 0, stream>>>(attn, w_proj, Mf);
  gemm_bt_kernel<0><<<dim3(DIMC / 128, HWN / 128, NBATCH), dim3(256), 0, stream>>>(
      Mf, qkvC + 768, (void*)out, DIMC, DIMC, CDIM, HWN,
      (unsigned long long)DIMC * DIMC, (unsigned long long)HWN * CDIM,
      (unsigned long long)DIMC * HWN);
}